// Round 3
// baseline (117.917 us; speedup 1.0000x reference)
//
#include <hip/hip_runtime.h>

#define MAX_POINTS 32
#define C_OUT 64
#define EPS 1e-5f

// ws layout (floats): 8 accumulator sets, each 16 floats (64 B apart).
// set s, moment i -> ws[s*16 + i]
//  i in [0..3]  : sum x   (sx, sy, sz, sw)
//  i in [4..13] : second moments xx,xy,xz,xw,yy,yz,yw,zz,zw,ww
//  i == 14      : valid-point count
#define NMOM 15
#define NSET 8

// ---------------- Pass 1: 15-scalar moment reduction (streaming, HBM-bound) --
__global__ __launch_bounds__(256) void vfe_stats(
    const float* __restrict__ x, const int* __restrict__ vnp,
    float* __restrict__ ws, int M)
{
    const int tid    = blockIdx.x * 256 + threadIdx.x;
    const int stride = gridDim.x * 256;
    const int total  = M * MAX_POINTS;            // flat float4 slots

    float a[NMOM];
    #pragma unroll
    for (int i = 0; i < NMOM; ++i) a[i] = 0.f;

    const float4* __restrict__ xq = (const float4*)x;
    for (int i = tid; i < total; i += stride) {
        const float4 q0 = xq[i];                  // UNCONDITIONAL: issues immediately
        const int   n   = vnp[i >> 5];            // independent load, overlaps q0
        const float mk  = ((i & 31) < n) ? 1.f : 0.f;
        const float qx = q0.x * mk, qy = q0.y * mk, qz = q0.z * mk, qw = q0.w * mk;
        a[0] += qx; a[1] += qy; a[2] += qz; a[3] += qw;
        a[4]  = fmaf(qx, qx, a[4]);
        a[5]  = fmaf(qx, qy, a[5]);
        a[6]  = fmaf(qx, qz, a[6]);
        a[7]  = fmaf(qx, qw, a[7]);
        a[8]  = fmaf(qy, qy, a[8]);
        a[9]  = fmaf(qy, qz, a[9]);
        a[10] = fmaf(qy, qw, a[10]);
        a[11] = fmaf(qz, qz, a[11]);
        a[12] = fmaf(qz, qw, a[12]);
        a[13] = fmaf(qw, qw, a[13]);
        a[14] += mk;
    }

    // wave reduce (64 lanes)
    #pragma unroll
    for (int i = 0; i < NMOM; ++i) {
        float v = a[i];
        #pragma unroll
        for (int off = 32; off > 0; off >>= 1)
            v += __shfl_down(v, off, 64);
        a[i] = v;
    }

    // block reduce: 4 waves -> LDS -> 15 atomics into this block's set
    __shared__ float bl[4][NMOM];
    const int lane = threadIdx.x & 63;
    const int wid  = threadIdx.x >> 6;
    if (lane == 0) {
        #pragma unroll
        for (int i = 0; i < NMOM; ++i) bl[wid][i] = a[i];
    }
    __syncthreads();
    if (threadIdx.x < NMOM) {
        const int i = threadIdx.x;
        const int set = blockIdx.x & (NSET - 1);  // spread over 8 L2 sectors
        atomicAdd(&ws[set * 16 + i], bl[0][i] + bl[1][i] + bl[2][i] + bl[3][i]);
    }
}

// ---------------- Pass 2: scalar-pipe point fetch, lane = channel -----------
__global__ __launch_bounds__(256) void vfe_out(
    const float* __restrict__ x, const int* __restrict__ vnp,
    const float* __restrict__ W, const float* __restrict__ b,
    const float* __restrict__ gamma, const float* __restrict__ beta,
    const float* __restrict__ ws, float* __restrict__ out, int M)
{
    const int lane = threadIdx.x & 63;            // channel
    // Force wave id into an SGPR so all point addresses are provably uniform
    // -> compiler selects s_load (SMEM pipe), scalar loop branch, no LDS.
    const int wid  = __builtin_amdgcn_readfirstlane(threadIdx.x >> 6);
    const int gw   = blockIdx.x * 4 + wid;        // global wave id, SGPR

    // Sum the 8 accumulator sets (uniform addresses -> s_load)
    float mom[NMOM];
    #pragma unroll
    for (int i = 0; i < NMOM; ++i) {
        float s = 0.f;
        #pragma unroll
        for (int j = 0; j < NSET; ++j) s += ws[j * 16 + i];
        mom[i] = s;
    }

    // Per-lane BN affine from the 15 moments
    const float4 w4  = ((const float4*)W)[lane];
    const float bias = b[lane];
    const float cnt  = mom[14];
    const float nv   = fmaxf(cnt, 1.0f);
    const float wdots = w4.x*mom[0] + w4.y*mom[1] + w4.z*mom[2] + w4.w*mom[3];
    const float mu   = (wdots + cnt * bias) / nv;
    const float q2 = mom[4]*w4.x*w4.x + mom[8]*w4.y*w4.y + mom[11]*w4.z*w4.z + mom[13]*w4.w*w4.w
                   + 2.f*(mom[5]*w4.x*w4.y + mom[6]*w4.x*w4.z + mom[7]*w4.x*w4.w
                        + mom[9]*w4.y*w4.z + mom[10]*w4.y*w4.w + mom[12]*w4.z*w4.w);
    const float SS  = q2 + 2.f*bias*wdots + cnt*bias*bias;   // sum h^2 over valid
    const float var = fmaxf(SS / nv - mu * mu, 0.f);
    const float A   = gamma[lane] * rsqrtf(var + EPS);
    const float B   = fmaf(-mu, A, beta[lane]);

    // 8 voxels per wave; point data fetched on the scalar pipe
    const int m_base = gw * 8;
    #pragma unroll
    for (int v = 0; v < 8; ++v) {
        const int m = m_base + v;
        if (m >= M) break;                        // uniform branch
        const int n = vnp[m];                     // uniform -> s_load
        const float* __restrict__ xr = x + (size_t)m * (MAX_POINTS * 4);
        float acc = 0.f;
        for (int p = 0; p < n; ++p) {             // scalar loop (n in SGPR)
            const float px = xr[p*4+0];           // uniform -> s_load_dwordx4
            const float py = xr[p*4+1];
            const float pz = xr[p*4+2];
            const float pw = xr[p*4+3];
            const float h = fmaf(px, w4.x, fmaf(py, w4.y,
                            fmaf(pz, w4.z, fmaf(pw, w4.w, bias))));
            acc += fmaxf(fmaf(h, A, B), 0.f);
        }
        const float rn = 1.0f / fmaxf((float)n, 1.0f);
        out[(size_t)m * C_OUT + lane] = acc * rn; // coalesced 256 B/wave store
    }
}

extern "C" void kernel_launch(void* const* d_in, const int* in_sizes, int n_in,
                              void* d_out, int out_size, void* d_ws, size_t ws_size,
                              hipStream_t stream) {
    const float* x     = (const float*)d_in[0];
    const int*   vnp   = (const int*)  d_in[1];
    const float* W     = (const float*)d_in[2];
    const float* b     = (const float*)d_in[3];
    const float* gamma = (const float*)d_in[4];
    const float* beta  = (const float*)d_in[5];
    float* out = (float*)d_out;
    float* ws  = (float*)d_ws;
    const int M = in_sizes[1];                    // 40000 voxels

    hipMemsetAsync(d_ws, 0, NSET * 16 * sizeof(float), stream);
    vfe_stats<<<2048, 256, 0, stream>>>(x, vnp, ws, M);
    const int nwaves = (M + 7) / 8;               // 8 voxels per wave
    const int nblk   = (nwaves + 3) / 4;          // 4 waves per block
    vfe_out<<<nblk, 256, 0, stream>>>(x, vnp, W, b, gamma, beta, ws, out, M);
}

// Round 4
// 117.653 us; speedup vs baseline: 1.0022x; 1.0022x over previous
//
#include <hip/hip_runtime.h>

#define MAX_POINTS 32
#define C_OUT 64
#define EPS 1e-5f

// ws layout (floats): 8 accumulator sets, each 16 floats (64 B apart).
// set s, moment i -> ws[s*16 + i]
//  i in [0..3]  : sum x   (sx, sy, sz, sw)
//  i in [4..13] : second moments xx,xy,xz,xw,yy,yz,yw,zz,zw,ww
//  i == 14      : valid-point count
#define NMOM 15
#define NSET 8

// ---------------- Pass 1: 15-scalar moment reduction (streaming) ------------
__global__ __launch_bounds__(256) void vfe_stats(
    const float* __restrict__ x, const int* __restrict__ vnp,
    float* __restrict__ ws, int M)
{
    const int tid    = blockIdx.x * 256 + threadIdx.x;
    const int stride = gridDim.x * 256;
    const int total  = M * MAX_POINTS;            // flat float4 slots

    float a[NMOM];
    #pragma unroll
    for (int i = 0; i < NMOM; ++i) a[i] = 0.f;

    const float4* __restrict__ xq = (const float4*)x;
    for (int i = tid; i < total; i += stride) {
        const float4 q0 = xq[i];                  // unconditional: issues immediately
        const int   n   = vnp[i >> 5];            // independent load, overlaps q0
        const float mk  = ((i & 31) < n) ? 1.f : 0.f;
        const float qx = q0.x * mk, qy = q0.y * mk, qz = q0.z * mk, qw = q0.w * mk;
        a[0] += qx; a[1] += qy; a[2] += qz; a[3] += qw;
        a[4]  = fmaf(qx, qx, a[4]);
        a[5]  = fmaf(qx, qy, a[5]);
        a[6]  = fmaf(qx, qz, a[6]);
        a[7]  = fmaf(qx, qw, a[7]);
        a[8]  = fmaf(qy, qy, a[8]);
        a[9]  = fmaf(qy, qz, a[9]);
        a[10] = fmaf(qy, qw, a[10]);
        a[11] = fmaf(qz, qz, a[11]);
        a[12] = fmaf(qz, qw, a[12]);
        a[13] = fmaf(qw, qw, a[13]);
        a[14] += mk;
    }

    // wave reduce (64 lanes)
    #pragma unroll
    for (int i = 0; i < NMOM; ++i) {
        float v = a[i];
        #pragma unroll
        for (int off = 32; off > 0; off >>= 1)
            v += __shfl_down(v, off, 64);
        a[i] = v;
    }

    // block reduce: 4 waves -> LDS -> 15 atomics into this block's set
    __shared__ float bl[4][NMOM];
    const int lane = threadIdx.x & 63;
    const int wid  = threadIdx.x >> 6;
    if (lane == 0) {
        #pragma unroll
        for (int i = 0; i < NMOM; ++i) bl[wid][i] = a[i];
    }
    __syncthreads();
    if (threadIdx.x < NMOM) {
        const int i = threadIdx.x;
        const int set = blockIdx.x & (NSET - 1);  // spread over 8 L2 sectors
        atomicAdd(&ws[set * 16 + i], bl[0][i] + bl[1][i] + bl[2][i] + bl[3][i]);
    }
}

// ---------------- Pass 2: fixed-unroll branchless bodies --------------------
// Wave = voxel stream (4 voxels/wave), lane = channel. Point loads are
// same-address-across-wave global float4 broadcasts (L1/L2-served, x is
// L3-resident from pass 1). Fixed trip count NP lets the compiler issue all
// NP loads back-to-back -> deep MLP, one wait amortized over the body.
template<int NP>
__device__ __forceinline__ float voxel_body(
    const float4* __restrict__ xq, int n,
    float4 w4, float bias, float A, float B)
{
    float acc0 = 0.f, acc1 = 0.f, acc2 = 0.f, acc3 = 0.f;
    #pragma unroll
    for (int p = 0; p < NP; ++p) {
        const float4 q = xq[p];
        const float h = fmaf(q.x, w4.x, fmaf(q.y, w4.y,
                        fmaf(q.z, w4.z, fmaf(q.w, w4.w, bias))));
        float v = fmaxf(fmaf(h, A, B), 0.f);
        if (p >= NP - 8) v = (p < n) ? v : 0.f;   // only last 8 need the mask
        if      ((p & 3) == 0) acc0 += v;
        else if ((p & 3) == 1) acc1 += v;
        else if ((p & 3) == 2) acc2 += v;
        else                   acc3 += v;
    }
    return (acc0 + acc1) + (acc2 + acc3);
}

__global__ __launch_bounds__(256) void vfe_out(
    const float* __restrict__ x, const int* __restrict__ vnp,
    const float* __restrict__ W, const float* __restrict__ b,
    const float* __restrict__ gamma, const float* __restrict__ beta,
    const float* __restrict__ ws, float* __restrict__ out, int M)
{
    const int lane = threadIdx.x & 63;            // channel
    const int wid  = threadIdx.x >> 6;
    const int gw   = blockIdx.x * 4 + wid;        // global wave id

    // Sum the 8 accumulator sets, vectorized (uniform float4 loads)
    const float4* __restrict__ ws4 = (const float4*)ws;
    float4 m4[4];
    #pragma unroll
    for (int k = 0; k < 4; ++k) {
        float4 s = ws4[k];
        #pragma unroll
        for (int j = 1; j < NSET; ++j) {
            const float4 t = ws4[j * 4 + k];
            s.x += t.x; s.y += t.y; s.z += t.z; s.w += t.w;
        }
        m4[k] = s;
    }
    const float mom[NMOM] = { m4[0].x, m4[0].y, m4[0].z, m4[0].w,
                              m4[1].x, m4[1].y, m4[1].z, m4[1].w,
                              m4[2].x, m4[2].y, m4[2].z, m4[2].w,
                              m4[3].x, m4[3].y, m4[3].z };

    // Per-lane BN affine from the 15 moments
    const float4 w4  = ((const float4*)W)[lane];
    const float bias = b[lane];
    const float cnt  = mom[14];
    const float nv   = fmaxf(cnt, 1.0f);
    const float wdots = w4.x*mom[0] + w4.y*mom[1] + w4.z*mom[2] + w4.w*mom[3];
    const float mu   = (wdots + cnt * bias) / nv;
    const float q2 = mom[4]*w4.x*w4.x + mom[8]*w4.y*w4.y + mom[11]*w4.z*w4.z + mom[13]*w4.w*w4.w
                   + 2.f*(mom[5]*w4.x*w4.y + mom[6]*w4.x*w4.z + mom[7]*w4.x*w4.w
                        + mom[9]*w4.y*w4.z + mom[10]*w4.y*w4.w + mom[12]*w4.z*w4.w);
    const float SS  = q2 + 2.f*bias*wdots + cnt*bias*bias;   // sum h^2 over valid
    const float var = fmaxf(SS / nv - mu * mu, 0.f);
    const float A   = gamma[lane] * rsqrtf(var + EPS);
    const float B   = fmaf(-mu, A, beta[lane]);

    // 4 voxels per wave
    const int m_base = gw * 4;
    #pragma unroll
    for (int v = 0; v < 4; ++v) {
        const int m = m_base + v;
        if (m >= M) break;                        // uniform branch
        const int n = vnp[m];                     // wave-uniform
        const float4* __restrict__ xq = (const float4*)x + (size_t)m * MAX_POINTS;
        float acc;
        if      (n > 24) acc = voxel_body<32>(xq, n, w4, bias, A, B);
        else if (n > 16) acc = voxel_body<24>(xq, n, w4, bias, A, B);
        else if (n >  8) acc = voxel_body<16>(xq, n, w4, bias, A, B);
        else if (n >  0) acc = voxel_body< 8>(xq, n, w4, bias, A, B);
        else             acc = 0.f;
        const float rn = 1.0f / fmaxf((float)n, 1.0f);
        out[(size_t)m * C_OUT + lane] = acc * rn; // coalesced 256 B/wave store
    }
}

extern "C" void kernel_launch(void* const* d_in, const int* in_sizes, int n_in,
                              void* d_out, int out_size, void* d_ws, size_t ws_size,
                              hipStream_t stream) {
    const float* x     = (const float*)d_in[0];
    const int*   vnp   = (const int*)  d_in[1];
    const float* W     = (const float*)d_in[2];
    const float* b     = (const float*)d_in[3];
    const float* gamma = (const float*)d_in[4];
    const float* beta  = (const float*)d_in[5];
    float* out = (float*)d_out;
    float* ws  = (float*)d_ws;
    const int M = in_sizes[1];                    // 40000 voxels

    hipMemsetAsync(d_ws, 0, NSET * 16 * sizeof(float), stream);
    vfe_stats<<<2048, 256, 0, stream>>>(x, vnp, ws, M);
    const int nwaves = (M + 3) / 4;               // 4 voxels per wave
    const int nblk   = (nwaves + 3) / 4;          // 4 waves per block
    vfe_out<<<nblk, 256, 0, stream>>>(x, vnp, W, b, gamma, beta, ws, out, M);
}